// Round 12
// baseline (163.800 us; speedup 1.0000x reference)
//
#include <hip/hip_runtime.h>
#include <hip/hip_bf16.h>

typedef short short8 __attribute__((ext_vector_type(8)));
typedef float float4v __attribute__((ext_vector_type(4)));
typedef unsigned short ushort4v __attribute__((ext_vector_type(4)));

static __device__ __forceinline__ short f2b(float f) {
    union { __hip_bfloat16 b; short s; } v;
    v.b = __float2bfloat16(f);   // RNE
    return v.s;
}
static __device__ __forceinline__ float b2f(unsigned short u) {
    union { float f; unsigned v; } x;
    x.v = ((unsigned)u) << 16;
    return x.f;
}

// ---------------------------------------------------------------------------
// setup: one dispatch, three disjoint block roles.
//  blocks 0..63   : BTs[n][k] = bf16( sum_m Wn[k][m] * out_w[64+m][n] )  and
//                   BTd[n][k] = bf16( sum_m Wn[k][m] * out_w[m][n] )
//                   (B^T of the collapsed weights, k-contiguous so a lane's
//                    8-element MFMA B-fragment is ONE aligned 16 B load)
//  block  64      : ka/qa in LDS -> Wk = Wn·ka, Wq = Wn·qa, escale
//  blocks 65..    : row_ptr via binary search over SORTED dst_idx
// ---------------------------------------------------------------------------
__global__ void __launch_bounds__(256) setup_kernel(
    const float* __restrict__ query, const float* __restrict__ key_w,
    const float* __restrict__ weight_e, const float* __restrict__ att_w,
    const float* __restrict__ Wn, const float* __restrict__ out_w,
    const int* __restrict__ dst_idx,
    unsigned short* __restrict__ BTs, unsigned short* __restrict__ BTd,
    float* __restrict__ Wk, float* __restrict__ Wq, float* __restrict__ escale,
    int* __restrict__ row_ptr, int n_nodes, int n_edges) {
    int b = blockIdx.x, t = threadIdx.x;
    if (b < 64) {
        int idx = b * 256 + t;        // 0..16383
        int mat = idx >> 13;          // 0 -> BTs (src side), 1 -> BTd (dst)
        int rem = idx & 8191;
        int n = rem >> 7, k = rem & 127;
        float s = 0.f;
        for (int m = 0; m < 64; ++m)
            s += Wn[k * 64 + m] * out_w[(mat ? m : 64 + m) * 64 + n];
        (mat ? BTd : BTs)[n * 128 + k] = (unsigned short)f2b(s);
    } else if (b == 64) {
        __shared__ float kq[128];     // [0:64)=ka, [64:128)=qa
        __shared__ float ep[64];
        if (t < 64) {                 // ka[t] = key_w[t][:] . att_w[64:128]
            float s = 0.f;
            for (int j = 0; j < 64; ++j) s += key_w[t * 64 + j] * att_w[64 + j];
            kq[t] = s;
        } else if (t < 128) {         // qa[i] = query[i][:] . att_w[0:64]
            int i = t - 64;
            float s = 0.f;
            for (int j = 0; j < 64; ++j) s += query[i * 64 + j] * att_w[j];
            kq[64 + i] = s;
        } else if (t < 192) {
            int j = t - 128;
            ep[j] = weight_e[j] * att_w[128 + j];
        }
        __syncthreads();
        if (t < 128) {                // Wk[i] = Wn[i][:] . ka
            float s = 0.f;
            for (int k = 0; k < 64; ++k) s += Wn[t * 64 + k] * kq[k];
            Wk[t] = s;
        } else {                      // Wq[i] = Wn[i][:] . qa
            int i = t - 128;
            float s = 0.f;
            for (int k = 0; k < 64; ++k) s += Wn[i * 64 + k] * kq[64 + k];
            Wq[i] = s;
        }
        if (t == 0) {
            float s = 0.f;
            for (int j = 0; j < 64; ++j) s += ep[j];
            escale[0] = s;
        }
    } else {
        int idx = (b - 65) * 256 + t;
        if (idx > n_nodes) return;
        int lo = 0, hi = n_edges;
        while (lo < hi) {
            int mid = (lo + hi) >> 1;
            if (dst_idx[mid] < idx) lo = mid + 1; else hi = mid;
        }
        row_ptr[idx] = lo;
    }
}

// ---------------------------------------------------------------------------
// gemm v3: NO LDS, NO barrier. B-fragments (16 x 16 B = the whole 16 KB BT,
// L1/L2-resident) are loaded ONCE per wave into 64 VGPRs, then each wave
// streams 2 row-tiles (32 rows) with only A-loads + MFMA + fused score.
// Grid split: blocks [0, nb) = src rows, [nb, 2nb) = dst rows (128 rows/blk).
//  src: hw2 = feat_src @ W2' (bf16) ; kscore = feat_src . Wk (fp32, fused)
//  dst: out = feat_dst @ W1' + out_b (fp32) ; qscore = feat_dst . Wq
// MFMA 16x16x32 bf16 (R5-validated): A-frag lane=A[rb+m15][kk*32+quad*8..+7];
// C/D col=lane&15, row=quad*4+reg.
// ---------------------------------------------------------------------------
__global__ void __launch_bounds__(256) gemm_kernel(
    const float* __restrict__ feat_src, const float* __restrict__ feat_dst,
    const unsigned short* __restrict__ BTs, const unsigned short* __restrict__ BTd,
    const float* __restrict__ Wk, const float* __restrict__ Wq,
    unsigned short* __restrict__ hw2, float* __restrict__ out,
    const float* __restrict__ out_b, float* __restrict__ kscore,
    float* __restrict__ qscore, int n_nodes, int nb) {
    int t = threadIdx.x;
    bool isSrc = (int)blockIdx.x < nb;
    int bs = isSrc ? blockIdx.x : blockIdx.x - nb;
    int wave = t >> 6, lane = t & 63;
    int m15 = lane & 15, quad = lane >> 4;
    const unsigned short* BT = isSrc ? BTs : BTd;
    const float* A = isSrc ? feat_src : feat_dst;
    const float* w = isSrc ? Wk : Wq;

    // B-fragments: register-resident for the whole wave lifetime
    short8 bf[4][4];
#pragma unroll
    for (int kk = 0; kk < 4; ++kk)
#pragma unroll
        for (int nt = 0; nt < 4; ++nt)
            bf[kk][nt] = *(const short8*)(BT + (nt * 16 + m15) * 128 + kk * 32 + quad * 8);
    // score-weight fragments (8 floats per lane)
    float4v w0[4], w1[4];
#pragma unroll
    for (int kk = 0; kk < 4; ++kk) {
        w0[kk] = *(const float4v*)(w + kk * 32 + quad * 8);
        w1[kk] = *(const float4v*)(w + kk * 32 + quad * 8 + 4);
    }

#pragma unroll
    for (int tt = 0; tt < 2; ++tt) {
        int rb = ((bs * 4 + wave) * 2 + tt) * 16;
        if (rb >= n_nodes) continue;   // N % 16 == 0 -> full tiles
        const float* Arow = A + (size_t)(rb + m15) * 128 + quad * 8;

        float4v acc[4] = {};
        float sk = 0.f;
#pragma unroll
        for (int kk = 0; kk < 4; ++kk) {
            float4v a0 = *(const float4v*)(Arow + kk * 32);
            float4v a1 = *(const float4v*)(Arow + kk * 32 + 4);
#pragma unroll
            for (int j = 0; j < 4; ++j) sk += a0[j] * w0[kk][j] + a1[j] * w1[kk][j];
            short8 a;
#pragma unroll
            for (int j = 0; j < 4; ++j) { a[j] = f2b(a0[j]); a[4 + j] = f2b(a1[j]); }
#pragma unroll
            for (int nt = 0; nt < 4; ++nt)
                acc[nt] = __builtin_amdgcn_mfma_f32_16x16x32_bf16(a, bf[kk][nt], acc[nt], 0, 0, 0);
        }
#pragma unroll
        for (int nt = 0; nt < 4; ++nt) {
            int col = nt * 16 + m15;
            float bv = isSrc ? 0.f : out_b[col];
#pragma unroll
            for (int r = 0; r < 4; ++r) {
                int row = rb + quad * 4 + r;
                if (isSrc) hw2[(size_t)row * 64 + col] = (unsigned short)f2b(acc[nt][r]);
                else       out[(size_t)row * 64 + col] = acc[nt][r] + bv;
            }
        }
        sk += __shfl_xor(sk, 16);
        sk += __shfl_xor(sk, 32);
        if (quad == 0) {
            if (isSrc) kscore[rb + m15] = sk;
            else       qscore[rb + m15] = sk;
        }
    }
}

// ---------------------------------------------------------------------------
// agg: TWO nodes per wave, no-max softmax via prefix scan.  (R10-validated,
// verbatim)
// ---------------------------------------------------------------------------
__global__ void __launch_bounds__(256) agg_kernel(
    const int* __restrict__ src_idx, const float* __restrict__ edge_w,
    const unsigned short* __restrict__ hw2, const float* __restrict__ kscore,
    const float* __restrict__ qscore, const float* __restrict__ escale_p,
    const float* __restrict__ att_b, const int* __restrict__ row_ptr,
    float* __restrict__ out, int n_nodes) {
    int wid = (int)((blockIdx.x * blockDim.x + threadIdx.x) >> 6);
    int lane = threadIdx.x & 63;
    int n0 = wid * 2;
    if (n0 >= n_nodes) return;
    int nCnt = (n0 + 1 < n_nodes) ? 2 : 1;
    int rp0 = row_ptr[n0];
    int rp1 = row_ptr[n0 + 1];
    int rp2 = (nCnt == 2) ? row_ptr[n0 + 2] : rp1;
    int total = rp2 - rp0;
    if (total == 0) return;
    float escale = escale_p[0];
    float bias = att_b[0];
    int eslot = lane >> 4, cg = lane & 15;

    if (total <= 64) {
        int m = rp1 - rp0;
        int s0 = 0; float w = 0.f;
        if (lane < total) {
            s0 = src_idx[rp0 + lane];
            float lg = qscore[n0 + (lane >= m ? 1 : 0)] + kscore[s0]
                     + edge_w[rp0 + lane] * escale + bias;
            lg = (lg > 0.f) ? lg : 0.2f * lg;
            w = __expf(fminf(lg, 80.f));
        }
        float pre = w;
#pragma unroll
        for (int off = 1; off < 64; off <<= 1) {
            float tv = __shfl_up(pre, off);
            if (lane >= off) pre += tv;
        }
        float sumAll = __shfl(pre, 63);
        float sum0 = (m > 0) ? __shfl(pre, m - 1) : 0.f;
        float sum1 = sumAll - sum0;
        float mySum = (lane >= m) ? sum1 : sum0;
        float alpha0 = w * (1.f / (mySum + 1e-16f));

        for (int j = 0; j < nCnt; ++j) {
            int sl = j ? m : 0;
            int deg = j ? (total - m) : m;
            if (deg == 0) continue;
            float ac0 = 0.f, ac1 = 0.f, ac2 = 0.f, ac3 = 0.f;
            for (int b = 0; b < deg; b += 4) {
                int eo = b + eslot;
                int idx = (eo < deg) ? (sl + eo) : sl;
                float alpha = __shfl(alpha0, idx);
                int s = __shfl(s0, idx);
                if (eo >= deg) alpha = 0.f;
                ushort4v h = *(const ushort4v*)(hw2 + (size_t)s * 64 + cg * 4);
                ac0 += alpha * b2f(h[0]);
                ac1 += alpha * b2f(h[1]);
                ac2 += alpha * b2f(h[2]);
                ac3 += alpha * b2f(h[3]);
            }
            ac0 += __shfl_xor(ac0, 16); ac0 += __shfl_xor(ac0, 32);
            ac1 += __shfl_xor(ac1, 16); ac1 += __shfl_xor(ac1, 32);
            ac2 += __shfl_xor(ac2, 16); ac2 += __shfl_xor(ac2, 32);
            ac3 += __shfl_xor(ac3, 16); ac3 += __shfl_xor(ac3, 32);
            if (lane < 16) {
                float* op = out + (size_t)(n0 + j) * 64 + lane * 4;
                float4v bb = *(const float4v*)op;
                bb[0] += ac0; bb[1] += ac1; bb[2] += ac2; bb[3] += ac3;
                *(float4v*)op = bb;
            }
        }
    } else {
        for (int j = 0; j < nCnt; ++j) {
            int start = (j == 0) ? rp0 : rp1;
            int deg = ((j == 0) ? rp1 : rp2) - start;
            if (deg == 0) continue;
            float qs = qscore[n0 + j];
            float ac0 = 0.f, ac1 = 0.f, ac2 = 0.f, ac3 = 0.f;
            if (deg <= 64) {
                int s0 = 0; float lg0 = -1e30f;
                if (lane < deg) {
                    s0 = src_idx[start + lane];
                    float lg = qs + kscore[s0] + edge_w[start + lane] * escale + bias;
                    lg0 = (lg > 0.f) ? lg : 0.2f * lg;
                }
                float mx = lg0;
#pragma unroll
                for (int off = 32; off; off >>= 1) mx = fmaxf(mx, __shfl_xor(mx, off));
                float a0 = __expf(lg0 - mx);
                float sm = a0;
#pragma unroll
                for (int off = 32; off; off >>= 1) sm += __shfl_xor(sm, off);
                float alpha0 = a0 * (1.f / (sm + 1e-16f));
                for (int b = 0; b < deg; b += 4) {
                    int eo = b + eslot;
                    int idx = (eo < deg) ? eo : 0;
                    float alpha = __shfl(alpha0, idx);
                    int s = __shfl(s0, idx);
                    if (eo >= deg) alpha = 0.f;
                    ushort4v h = *(const ushort4v*)(hw2 + (size_t)s * 64 + cg * 4);
                    ac0 += alpha * b2f(h[0]);
                    ac1 += alpha * b2f(h[1]);
                    ac2 += alpha * b2f(h[2]);
                    ac3 += alpha * b2f(h[3]);
                }
            } else {
                float mx = -1e30f, sm = 0.f;
                for (int eo = lane; eo < deg; eo += 64) {
                    int s = src_idx[start + eo];
                    float lg = qs + kscore[s] + edge_w[start + eo] * escale + bias;
                    lg = (lg > 0.f) ? lg : 0.2f * lg;
                    float nm = fmaxf(mx, lg);
                    sm = sm * __expf(mx - nm) + __expf(lg - nm);
                    mx = nm;
                }
                for (int off = 32; off; off >>= 1) {
                    float m2 = __shfl_xor(mx, off);
                    float s2 = __shfl_xor(sm, off);
                    float nm = fmaxf(mx, m2);
                    sm = sm * __expf(mx - nm) + s2 * __expf(m2 - nm);
                    mx = nm;
                }
                float inv = 1.f / (sm + 1e-16f);
                for (int b = 0; b < deg; b += 4) {
                    int eo = b + eslot;
                    bool valid = eo < deg;
                    int e = start + (valid ? eo : 0);
                    int s = src_idx[e];
                    float lg = qs + kscore[s] + edge_w[e] * escale + bias;
                    lg = (lg > 0.f) ? lg : 0.2f * lg;
                    float alpha = valid ? __expf(lg - mx) * inv : 0.f;
                    ushort4v h = *(const ushort4v*)(hw2 + (size_t)s * 64 + cg * 4);
                    ac0 += alpha * b2f(h[0]);
                    ac1 += alpha * b2f(h[1]);
                    ac2 += alpha * b2f(h[2]);
                    ac3 += alpha * b2f(h[3]);
                }
            }
            ac0 += __shfl_xor(ac0, 16); ac0 += __shfl_xor(ac0, 32);
            ac1 += __shfl_xor(ac1, 16); ac1 += __shfl_xor(ac1, 32);
            ac2 += __shfl_xor(ac2, 16); ac2 += __shfl_xor(ac2, 32);
            ac3 += __shfl_xor(ac3, 16); ac3 += __shfl_xor(ac3, 32);
            if (lane < 16) {
                float* op = out + (size_t)(n0 + j) * 64 + lane * 4;
                float4v bb = *(const float4v*)op;
                bb[0] += ac0; bb[1] += ac1; bb[2] += ac2; bb[3] += ac3;
                *(float4v*)op = bb;
            }
        }
    }
}

extern "C" void kernel_launch(void* const* d_in, const int* in_sizes, int n_in,
                              void* d_out, int out_size, void* d_ws, size_t ws_size,
                              hipStream_t stream) {
    const float* feat_src = (const float*)d_in[0];
    const float* feat_dst = (const float*)d_in[1];
    const float* edge_w   = (const float*)d_in[2];
    const int*   src_idx  = (const int*)d_in[3];
    const int*   dst_idx  = (const int*)d_in[4];
    const float* weight_n = (const float*)d_in[5];
    const float* weight_e = (const float*)d_in[6];
    const float* query    = (const float*)d_in[7];
    const float* key_w    = (const float*)d_in[8];
    const float* att_w    = (const float*)d_in[9];
    const float* att_b    = (const float*)d_in[10];
    const float* out_w    = (const float*)d_in[11];
    const float* out_b    = (const float*)d_in[12];
    float* out = (float*)d_out;

    int n_nodes = in_sizes[0] / 128;  // 50000
    int n_edges = in_sizes[3];        // 800000

    // workspace layout (~7 MB), all segments 16B-aligned
    char* p = (char*)d_ws;
    unsigned short* hw2 = (unsigned short*)p;  p += (size_t)n_nodes * 64 * 2;
    float* kscore = (float*)p;  p += (size_t)n_nodes * 4;
    float* qscore = (float*)p;  p += (size_t)n_nodes * 4;
    unsigned short* BTs = (unsigned short*)p;  p += 64 * 128 * 2;   // 16 KB
    unsigned short* BTd = (unsigned short*)p;  p += 64 * 128 * 2;   // 16 KB
    float* Wk     = (float*)p;  p += 128 * 4;
    float* Wq     = (float*)p;  p += 128 * 4;
    float* escale = (float*)p;  p += 64;
    int*  row_ptr = (int*)p;

    int rp_blocks = (n_nodes + 1 + 255) / 256;
    hipLaunchKernelGGL(setup_kernel, dim3(65 + rp_blocks), dim3(256), 0, stream,
                       query, key_w, weight_e, att_w, weight_n, out_w, dst_idx,
                       BTs, BTd, Wk, Wq, escale, row_ptr, n_nodes, n_edges);

    int nb = (n_nodes + 127) / 128;   // 391 blocks/side, 128 rows/block
    hipLaunchKernelGGL(gemm_kernel, dim3(2 * nb), dim3(256), 0, stream,
                       feat_src, feat_dst, BTs, BTd, Wk, Wq,
                       hw2, out, out_b, kscore, qscore, n_nodes, nb);

    int n_waves = (n_nodes + 1) / 2;  // 2 nodes per wave
    hipLaunchKernelGGL(agg_kernel, dim3((n_waves + 3) / 4), dim3(256), 0, stream,
                       src_idx, edge_w, hw2, kscore, qscore,
                       escale, att_b, row_ptr, out, n_nodes);
}

// Round 13
// 153.271 us; speedup vs baseline: 1.0687x; 1.0687x over previous
//
#include <hip/hip_runtime.h>
#include <hip/hip_bf16.h>

typedef short short8 __attribute__((ext_vector_type(8)));
typedef float float4v __attribute__((ext_vector_type(4)));
typedef unsigned short ushort4v __attribute__((ext_vector_type(4)));

static __device__ __forceinline__ short f2b(float f) {
    union { __hip_bfloat16 b; short s; } v;
    v.b = __float2bfloat16(f);   // RNE
    return v.s;
}
static __device__ __forceinline__ float b2f(unsigned short u) {
    union { float f; unsigned v; } x;
    x.v = ((unsigned)u) << 16;
    return x.f;
}

// ---------------------------------------------------------------------------
// setup: one dispatch, three disjoint block roles.  (R12-validated)
//  blocks 0..63   : BTs[n][k] = bf16( sum_m Wn[k][m] * out_w[64+m][n] )
//                   BTd[n][k] = bf16( sum_m Wn[k][m] * out_w[m][n] )
//                   (B^T, k-contiguous: a lane's 8-elem B-fragment = 16 B)
//  block  64      : ka/qa in LDS -> Wk = Wn·ka, Wq = Wn·qa, escale
//  blocks 65..    : row_ptr via binary search over SORTED dst_idx
// ---------------------------------------------------------------------------
__global__ void __launch_bounds__(256) setup_kernel(
    const float* __restrict__ query, const float* __restrict__ key_w,
    const float* __restrict__ weight_e, const float* __restrict__ att_w,
    const float* __restrict__ Wn, const float* __restrict__ out_w,
    const int* __restrict__ dst_idx,
    unsigned short* __restrict__ BTs, unsigned short* __restrict__ BTd,
    float* __restrict__ Wk, float* __restrict__ Wq, float* __restrict__ escale,
    int* __restrict__ row_ptr, int n_nodes, int n_edges) {
    int b = blockIdx.x, t = threadIdx.x;
    if (b < 64) {
        int idx = b * 256 + t;        // 0..16383
        int mat = idx >> 13;          // 0 -> BTs (src side), 1 -> BTd (dst)
        int rem = idx & 8191;
        int n = rem >> 7, k = rem & 127;
        float s = 0.f;
        for (int m = 0; m < 64; ++m)
            s += Wn[k * 64 + m] * out_w[(mat ? m : 64 + m) * 64 + n];
        (mat ? BTd : BTs)[n * 128 + k] = (unsigned short)f2b(s);
    } else if (b == 64) {
        __shared__ float kq[128];     // [0:64)=ka, [64:128)=qa
        __shared__ float ep[64];
        if (t < 64) {                 // ka[t] = key_w[t][:] . att_w[64:128]
            float s = 0.f;
            for (int j = 0; j < 64; ++j) s += key_w[t * 64 + j] * att_w[64 + j];
            kq[t] = s;
        } else if (t < 128) {         // qa[i] = query[i][:] . att_w[0:64]
            int i = t - 64;
            float s = 0.f;
            for (int j = 0; j < 64; ++j) s += query[i * 64 + j] * att_w[j];
            kq[64 + i] = s;
        } else if (t < 192) {
            int j = t - 128;
            ep[j] = weight_e[j] * att_w[128 + j];
        }
        __syncthreads();
        if (t < 128) {                // Wk[i] = Wn[i][:] . ka
            float s = 0.f;
            for (int k = 0; k < 64; ++k) s += Wn[t * 64 + k] * kq[k];
            Wk[t] = s;
        } else {                      // Wq[i] = Wn[i][:] . qa
            int i = t - 128;
            float s = 0.f;
            for (int k = 0; k < 64; ++k) s += Wn[i * 64 + k] * kq[64 + k];
            Wq[i] = s;
        }
        if (t == 0) {
            float s = 0.f;
            for (int j = 0; j < 64; ++j) s += ep[j];
            escale[0] = s;
        }
    } else {
        int idx = (b - 65) * 256 + t;
        if (idx > n_nodes) return;
        int lo = 0, hi = n_edges;
        while (lo < hi) {
            int mid = (lo + hi) >> 1;
            if (dst_idx[mid] < idx) lo = mid + 1; else hi = mid;
        }
        row_ptr[idx] = lo;
    }
}

// ---------------------------------------------------------------------------
// gemm v4: back to LDS-staged B (R12's register-B regressed), but ONE tile
// per wave -> 6250 waves (6.1/SIMD, was 3.05) to hide the A-load latency.
// 64 rows/block, 4 waves. A-fragment loads are issued BEFORE the staging
// barrier (independent of LDS) to overlap HBM latency with B staging.
// Staging copies bf16 fragment-ready BT global -> LDS (+8-pad rows, 16 B
// aligned 2-way-conflict-free, no converts).
// Grid split: blocks [0, nb) = src rows, [nb, 2nb) = dst rows.
//  src: hw2 = feat_src @ W2' (bf16) ; kscore = feat_src . Wk (fp32, fused)
//  dst: out = feat_dst @ W1' + out_b (fp32) ; qscore = feat_dst . Wq
// MFMA 16x16x32 bf16 (R5-validated): A-frag lane=A[rb+m15][kk*32+quad*8..+7];
// C/D col=lane&15, row=quad*4+reg.
// ---------------------------------------------------------------------------
__global__ void __launch_bounds__(256) gemm_kernel(
    const float* __restrict__ feat_src, const float* __restrict__ feat_dst,
    const unsigned short* __restrict__ BTs, const unsigned short* __restrict__ BTd,
    const float* __restrict__ Wk, const float* __restrict__ Wq,
    unsigned short* __restrict__ hw2, float* __restrict__ out,
    const float* __restrict__ out_b, float* __restrict__ kscore,
    float* __restrict__ qscore, int n_nodes, int nb) {
    __shared__ __align__(16) unsigned short BT[64 * 136];  // +8 pad
    int t = threadIdx.x;
    bool isSrc = (int)blockIdx.x < nb;
    int bs = isSrc ? blockIdx.x : blockIdx.x - nb;
    int wave = t >> 6, lane = t & 63;
    int m15 = lane & 15, quad = lane >> 4;

    int rb = bs * 64 + wave * 16;
    bool valid = rb < n_nodes;

    // --- A-fragment loads first: overlap HBM latency with B staging ---
    const float* A = isSrc ? feat_src : feat_dst;
    float4v a0[4], a1[4];
    if (valid) {
        const float* Arow = A + (size_t)(rb + m15) * 128 + quad * 8;
#pragma unroll
        for (int kk = 0; kk < 4; ++kk) {
            a0[kk] = *(const float4v*)(Arow + kk * 32);
            a1[kk] = *(const float4v*)(Arow + kk * 32 + 4);
        }
    }

    // --- stage bf16 BT -> LDS (1024 x 16 B chunks, 4 per thread) ---
    const unsigned short* BTg = isSrc ? BTs : BTd;
#pragma unroll
    for (int i = 0; i < 4; ++i) {
        int j = i * 256 + t;            // 0..1023
        int n = j >> 4, k8 = (j & 15) * 8;
        *(short8*)(&BT[n * 136 + k8]) = *(const short8*)(BTg + n * 128 + k8);
    }
    __syncthreads();
    if (!valid) return;

    // --- fused score + convert + MFMA ---
    const float* w = isSrc ? Wk : Wq;
    float4v acc[4] = {};
    float sk = 0.f;
#pragma unroll
    for (int kk = 0; kk < 4; ++kk) {
        float4v w0 = *(const float4v*)(w + kk * 32 + quad * 8);
        float4v w1 = *(const float4v*)(w + kk * 32 + quad * 8 + 4);
#pragma unroll
        for (int j = 0; j < 4; ++j) sk += a0[kk][j] * w0[j] + a1[kk][j] * w1[j];
        short8 a;
#pragma unroll
        for (int j = 0; j < 4; ++j) { a[j] = f2b(a0[kk][j]); a[4 + j] = f2b(a1[kk][j]); }
#pragma unroll
        for (int nt = 0; nt < 4; ++nt) {
            short8 bb = *(const short8*)(&BT[(nt * 16 + m15) * 136 + kk * 32 + quad * 8]);
            acc[nt] = __builtin_amdgcn_mfma_f32_16x16x32_bf16(a, bb, acc[nt], 0, 0, 0);
        }
    }
#pragma unroll
    for (int nt = 0; nt < 4; ++nt) {
        int col = nt * 16 + m15;
        float bv = isSrc ? 0.f : out_b[col];
#pragma unroll
        for (int r = 0; r < 4; ++r) {
            int row = rb + quad * 4 + r;
            if (isSrc) hw2[(size_t)row * 64 + col] = (unsigned short)f2b(acc[nt][r]);
            else       out[(size_t)row * 64 + col] = acc[nt][r] + bv;
        }
    }
    sk += __shfl_xor(sk, 16);
    sk += __shfl_xor(sk, 32);
    if (quad == 0) {
        if (isSrc) kscore[rb + m15] = sk;
        else       qscore[rb + m15] = sk;
    }
}

// ---------------------------------------------------------------------------
// agg: TWO nodes per wave, no-max softmax via prefix scan.  (R10-validated,
// verbatim)
// ---------------------------------------------------------------------------
__global__ void __launch_bounds__(256) agg_kernel(
    const int* __restrict__ src_idx, const float* __restrict__ edge_w,
    const unsigned short* __restrict__ hw2, const float* __restrict__ kscore,
    const float* __restrict__ qscore, const float* __restrict__ escale_p,
    const float* __restrict__ att_b, const int* __restrict__ row_ptr,
    float* __restrict__ out, int n_nodes) {
    int wid = (int)((blockIdx.x * blockDim.x + threadIdx.x) >> 6);
    int lane = threadIdx.x & 63;
    int n0 = wid * 2;
    if (n0 >= n_nodes) return;
    int nCnt = (n0 + 1 < n_nodes) ? 2 : 1;
    int rp0 = row_ptr[n0];
    int rp1 = row_ptr[n0 + 1];
    int rp2 = (nCnt == 2) ? row_ptr[n0 + 2] : rp1;
    int total = rp2 - rp0;
    if (total == 0) return;
    float escale = escale_p[0];
    float bias = att_b[0];
    int eslot = lane >> 4, cg = lane & 15;

    if (total <= 64) {
        int m = rp1 - rp0;
        int s0 = 0; float w = 0.f;
        if (lane < total) {
            s0 = src_idx[rp0 + lane];
            float lg = qscore[n0 + (lane >= m ? 1 : 0)] + kscore[s0]
                     + edge_w[rp0 + lane] * escale + bias;
            lg = (lg > 0.f) ? lg : 0.2f * lg;
            w = __expf(fminf(lg, 80.f));
        }
        float pre = w;
#pragma unroll
        for (int off = 1; off < 64; off <<= 1) {
            float tv = __shfl_up(pre, off);
            if (lane >= off) pre += tv;
        }
        float sumAll = __shfl(pre, 63);
        float sum0 = (m > 0) ? __shfl(pre, m - 1) : 0.f;
        float sum1 = sumAll - sum0;
        float mySum = (lane >= m) ? sum1 : sum0;
        float alpha0 = w * (1.f / (mySum + 1e-16f));

        for (int j = 0; j < nCnt; ++j) {
            int sl = j ? m : 0;
            int deg = j ? (total - m) : m;
            if (deg == 0) continue;
            float ac0 = 0.f, ac1 = 0.f, ac2 = 0.f, ac3 = 0.f;
            for (int b = 0; b < deg; b += 4) {
                int eo = b + eslot;
                int idx = (eo < deg) ? (sl + eo) : sl;
                float alpha = __shfl(alpha0, idx);
                int s = __shfl(s0, idx);
                if (eo >= deg) alpha = 0.f;
                ushort4v h = *(const ushort4v*)(hw2 + (size_t)s * 64 + cg * 4);
                ac0 += alpha * b2f(h[0]);
                ac1 += alpha * b2f(h[1]);
                ac2 += alpha * b2f(h[2]);
                ac3 += alpha * b2f(h[3]);
            }
            ac0 += __shfl_xor(ac0, 16); ac0 += __shfl_xor(ac0, 32);
            ac1 += __shfl_xor(ac1, 16); ac1 += __shfl_xor(ac1, 32);
            ac2 += __shfl_xor(ac2, 16); ac2 += __shfl_xor(ac2, 32);
            ac3 += __shfl_xor(ac3, 16); ac3 += __shfl_xor(ac3, 32);
            if (lane < 16) {
                float* op = out + (size_t)(n0 + j) * 64 + lane * 4;
                float4v bb = *(const float4v*)op;
                bb[0] += ac0; bb[1] += ac1; bb[2] += ac2; bb[3] += ac3;
                *(float4v*)op = bb;
            }
        }
    } else {
        for (int j = 0; j < nCnt; ++j) {
            int start = (j == 0) ? rp0 : rp1;
            int deg = ((j == 0) ? rp1 : rp2) - start;
            if (deg == 0) continue;
            float qs = qscore[n0 + j];
            float ac0 = 0.f, ac1 = 0.f, ac2 = 0.f, ac3 = 0.f;
            if (deg <= 64) {
                int s0 = 0; float lg0 = -1e30f;
                if (lane < deg) {
                    s0 = src_idx[start + lane];
                    float lg = qs + kscore[s0] + edge_w[start + lane] * escale + bias;
                    lg0 = (lg > 0.f) ? lg : 0.2f * lg;
                }
                float mx = lg0;
#pragma unroll
                for (int off = 32; off; off >>= 1) mx = fmaxf(mx, __shfl_xor(mx, off));
                float a0 = __expf(lg0 - mx);
                float sm = a0;
#pragma unroll
                for (int off = 32; off; off >>= 1) sm += __shfl_xor(sm, off);
                float alpha0 = a0 * (1.f / (sm + 1e-16f));
                for (int b = 0; b < deg; b += 4) {
                    int eo = b + eslot;
                    int idx = (eo < deg) ? eo : 0;
                    float alpha = __shfl(alpha0, idx);
                    int s = __shfl(s0, idx);
                    if (eo >= deg) alpha = 0.f;
                    ushort4v h = *(const ushort4v*)(hw2 + (size_t)s * 64 + cg * 4);
                    ac0 += alpha * b2f(h[0]);
                    ac1 += alpha * b2f(h[1]);
                    ac2 += alpha * b2f(h[2]);
                    ac3 += alpha * b2f(h[3]);
                }
            } else {
                float mx = -1e30f, sm = 0.f;
                for (int eo = lane; eo < deg; eo += 64) {
                    int s = src_idx[start + eo];
                    float lg = qs + kscore[s] + edge_w[start + eo] * escale + bias;
                    lg = (lg > 0.f) ? lg : 0.2f * lg;
                    float nm = fmaxf(mx, lg);
                    sm = sm * __expf(mx - nm) + __expf(lg - nm);
                    mx = nm;
                }
                for (int off = 32; off; off >>= 1) {
                    float m2 = __shfl_xor(mx, off);
                    float s2 = __shfl_xor(sm, off);
                    float nm = fmaxf(mx, m2);
                    sm = sm * __expf(mx - nm) + s2 * __expf(m2 - nm);
                    mx = nm;
                }
                float inv = 1.f / (sm + 1e-16f);
                for (int b = 0; b < deg; b += 4) {
                    int eo = b + eslot;
                    bool valid = eo < deg;
                    int e = start + (valid ? eo : 0);
                    int s = src_idx[e];
                    float lg = qs + kscore[s] + edge_w[e] * escale + bias;
                    lg = (lg > 0.f) ? lg : 0.2f * lg;
                    float alpha = valid ? __expf(lg - mx) * inv : 0.f;
                    ushort4v h = *(const ushort4v*)(hw2 + (size_t)s * 64 + cg * 4);
                    ac0 += alpha * b2f(h[0]);
                    ac1 += alpha * b2f(h[1]);
                    ac2 += alpha * b2f(h[2]);
                    ac3 += alpha * b2f(h[3]);
                }
            }
            ac0 += __shfl_xor(ac0, 16); ac0 += __shfl_xor(ac0, 32);
            ac1 += __shfl_xor(ac1, 16); ac1 += __shfl_xor(ac1, 32);
            ac2 += __shfl_xor(ac2, 16); ac2 += __shfl_xor(ac2, 32);
            ac3 += __shfl_xor(ac3, 16); ac3 += __shfl_xor(ac3, 32);
            if (lane < 16) {
                float* op = out + (size_t)(n0 + j) * 64 + lane * 4;
                float4v bb = *(const float4v*)op;
                bb[0] += ac0; bb[1] += ac1; bb[2] += ac2; bb[3] += ac3;
                *(float4v*)op = bb;
            }
        }
    }
}

extern "C" void kernel_launch(void* const* d_in, const int* in_sizes, int n_in,
                              void* d_out, int out_size, void* d_ws, size_t ws_size,
                              hipStream_t stream) {
    const float* feat_src = (const float*)d_in[0];
    const float* feat_dst = (const float*)d_in[1];
    const float* edge_w   = (const float*)d_in[2];
    const int*   src_idx  = (const int*)d_in[3];
    const int*   dst_idx  = (const int*)d_in[4];
    const float* weight_n = (const float*)d_in[5];
    const float* weight_e = (const float*)d_in[6];
    const float* query    = (const float*)d_in[7];
    const float* key_w    = (const float*)d_in[8];
    const float* att_w    = (const float*)d_in[9];
    const float* att_b    = (const float*)d_in[10];
    const float* out_w    = (const float*)d_in[11];
    const float* out_b    = (const float*)d_in[12];
    float* out = (float*)d_out;

    int n_nodes = in_sizes[0] / 128;  // 50000
    int n_edges = in_sizes[3];        // 800000

    // workspace layout (~7 MB), all segments 16B-aligned
    char* p = (char*)d_ws;
    unsigned short* hw2 = (unsigned short*)p;  p += (size_t)n_nodes * 64 * 2;
    float* kscore = (float*)p;  p += (size_t)n_nodes * 4;
    float* qscore = (float*)p;  p += (size_t)n_nodes * 4;
    unsigned short* BTs = (unsigned short*)p;  p += 64 * 128 * 2;   // 16 KB
    unsigned short* BTd = (unsigned short*)p;  p += 64 * 128 * 2;   // 16 KB
    float* Wk     = (float*)p;  p += 128 * 4;
    float* Wq     = (float*)p;  p += 128 * 4;
    float* escale = (float*)p;  p += 64;
    int*  row_ptr = (int*)p;

    int rp_blocks = (n_nodes + 1 + 255) / 256;
    hipLaunchKernelGGL(setup_kernel, dim3(65 + rp_blocks), dim3(256), 0, stream,
                       query, key_w, weight_e, att_w, weight_n, out_w, dst_idx,
                       BTs, BTd, Wk, Wq, escale, row_ptr, n_nodes, n_edges);

    int nb = (n_nodes + 63) / 64;     // 782 blocks/side, 64 rows/block
    hipLaunchKernelGGL(gemm_kernel, dim3(2 * nb), dim3(256), 0, stream,
                       feat_src, feat_dst, BTs, BTd, Wk, Wq,
                       hw2, out, out_b, kscore, qscore, n_nodes, nb);

    int n_waves = (n_nodes + 1) / 2;  // 2 nodes per wave
    hipLaunchKernelGGL(agg_kernel, dim3((n_waves + 3) / 4), dim3(256), 0, stream,
                       src_idx, edge_w, hw2, kscore, qscore,
                       escale, att_b, row_ptr, out, n_nodes);
}